// Round 2
// baseline (1409.755 us; speedup 1.0000x reference)
//
#include <hip/hip_runtime.h>
#include <math.h>

#define NN 2048
#define TT 32
#define FIN 5
#define HH 64
#define G4 256     // 4*H
#define GATH 16

// ---------- helpers ----------
__device__ __forceinline__ float sigf(float x) {
    return 1.0f / (1.0f + __expf(-x));
}
__device__ __forceinline__ float tanh_fast(float x) {
    x = fminf(fmaxf(x, -15.0f), 15.0f);
    float t = __expf(2.0f * x);
    return (t - 1.0f) / (t + 1.0f);
}
__device__ __forceinline__ float dot4(float4 a, float4 b) {
    return a.x * b.x + a.y * b.y + a.z * b.z + a.w * b.w;
}

// ---------- fused 2-layer LSTM ----------
// grid 256 blocks x 768 threads; 8 nodes per block; layer-1 pipelined one
// step behind layer-0.
//
// Gate phase decomposition (anti-spill + anti-LDS-broadcast):
//   each worker thread owns 4 gate rows x a 16-float quarter of the dot
//   => 16 float4 = 64 weight VGPRs (fits; R1's 128-weight layout spilled:
//   VGPR capped at 128, 580MB scratch FETCH).
//   L0 workers: tid 0..255   (q = tid>>6, 64 lanes x 4 rows)
//   L1 workers: tid 256..767 (p = x-part/h-part, q = quarter)
// Partial sums go through LDS; combine phase sums partials + pointwise.
#define LNB 8
__global__ __launch_bounds__(768, 3) void k_lstm(
    const float* __restrict__ inputs,
    const float* __restrict__ w_ih0, const float* __restrict__ w_hh0,
    const float* __restrict__ b_ih0, const float* __restrict__ b_hh0,
    const float* __restrict__ w_ih1, const float* __restrict__ w_hh1,
    const float* __restrict__ b_ih1, const float* __restrict__ b_hh1,
    float* __restrict__ x_out)
{
    __shared__ float x_lds[LNB * TT * FIN];    // 1280
    __shared__ float h0_lds[LNB * HH];         // 512
    __shared__ float h1_lds[LNB * HH];         // 512
    __shared__ float gp0[4 * LNB * G4];        // 8192:  [q][nb][row]
    __shared__ float gp1[8 * LNB * G4];        // 16384: [p*4+q][nb][row]

    const int tid = threadIdx.x;
    const int n0 = blockIdx.x * LNB;

    // stage inputs (contiguous 1280 floats) + zero h state
    for (int idx = tid; idx < LNB * TT * FIN; idx += 768)
        x_lds[idx] = inputs[n0 * (TT * FIN) + idx];
    for (int idx = tid; idx < LNB * HH; idx += 768) {
        h0_lds[idx] = 0.0f;
        h1_lds[idx] = 0.0f;
    }

    // ---- gate-worker setup ----
    const bool isL0w = (tid < 256);
    int q, rbase, p = 0;
    {
        if (isL0w) {
            q = tid >> 6;
            rbase = (tid & 63) * 4;
        } else {
            int lid = tid - 256;
            p = lid >> 8;              // 0: x-part (w_ih1), 1: h-part (w_hh1)
            q = (lid >> 6) & 3;
            rbase = (lid & 63) * 4;
        }
    }
    // 4 rows x 4 float4 of weights = 64 VGPRs
    float4 wq[4][4];
    {
        const float* wsrc = isL0w ? w_hh0 : (p == 0 ? w_ih1 : w_hh1);
        #pragma unroll
        for (int j = 0; j < 4; ++j) {
            const float4* prow = (const float4*)(wsrc + (rbase + j) * HH + q * 16);
            wq[j][0] = prow[0]; wq[j][1] = prow[1];
            wq[j][2] = prow[2]; wq[j][3] = prow[3];
        }
    }
    // bias + input weights (only the q==0 / (p==0,q==0) threads carry them)
    float4 bias4 = make_float4(0.f, 0.f, 0.f, 0.f);
    float xw[4][FIN];
    const bool hasBias = (isL0w && q == 0) || (!isL0w && p == 0 && q == 0);
    if (hasBias) {
        const float* bi = isL0w ? b_ih0 : b_ih1;
        const float* bh = isL0w ? b_hh0 : b_hh1;
        bias4.x = bi[rbase + 0] + bh[rbase + 0];
        bias4.y = bi[rbase + 1] + bh[rbase + 1];
        bias4.z = bi[rbase + 2] + bh[rbase + 2];
        bias4.w = bi[rbase + 3] + bh[rbase + 3];
    }
    if (isL0w && q == 0) {
        #pragma unroll
        for (int j = 0; j < 4; ++j)
            #pragma unroll
            for (int f = 0; f < FIN; ++f)
                xw[j][f] = w_ih0[(rbase + j) * FIN + f];
    }

    // ---- combine-role setup ----
    // L0 combine: tid 0..255, 2 cells each (cnb=tid>>5, k=tid&31 and +32)
    // L1 combine: tid 256..767, 1 cell each (cnb=lid>>6, k=lid&63)
    const int c0nb = tid >> 5, c0k = tid & 31;
    const int c1nb = (tid - 256) >> 6, c1k = (tid - 256) & 63;
    float c_s0a = 0.0f, c_s0b = 0.0f, c_s1 = 0.0f;

    __syncthreads();

    for (int it = 0; it <= TT; ++it) {
        // ======== gate phase ========
        if (isL0w) {
            if (it < TT) {
                #pragma unroll 2
                for (int nb = 0; nb < LNB; ++nb) {
                    const float4* hq = (const float4*)&h0_lds[nb * HH + q * 16];
                    float4 h0v = hq[0], h1v = hq[1], h2v = hq[2], h3v = hq[3];
                    float4 acc;
                    acc.x = dot4(wq[0][0], h0v) + dot4(wq[0][1], h1v) + dot4(wq[0][2], h2v) + dot4(wq[0][3], h3v);
                    acc.y = dot4(wq[1][0], h0v) + dot4(wq[1][1], h1v) + dot4(wq[1][2], h2v) + dot4(wq[1][3], h3v);
                    acc.z = dot4(wq[2][0], h0v) + dot4(wq[2][1], h1v) + dot4(wq[2][2], h2v) + dot4(wq[2][3], h3v);
                    acc.w = dot4(wq[3][0], h0v) + dot4(wq[3][1], h1v) + dot4(wq[3][2], h2v) + dot4(wq[3][3], h3v);
                    if (q == 0) {
                        const float* xv = &x_lds[nb * (TT * FIN) + it * FIN];
                        float x0 = xv[0], x1 = xv[1], x2 = xv[2], x3 = xv[3], x4 = xv[4];
                        acc.x += bias4.x + xw[0][0]*x0 + xw[0][1]*x1 + xw[0][2]*x2 + xw[0][3]*x3 + xw[0][4]*x4;
                        acc.y += bias4.y + xw[1][0]*x0 + xw[1][1]*x1 + xw[1][2]*x2 + xw[1][3]*x3 + xw[1][4]*x4;
                        acc.z += bias4.z + xw[2][0]*x0 + xw[2][1]*x1 + xw[2][2]*x2 + xw[2][3]*x3 + xw[2][4]*x4;
                        acc.w += bias4.w + xw[3][0]*x0 + xw[3][1]*x1 + xw[3][2]*x2 + xw[3][3]*x3 + xw[3][4]*x4;
                    }
                    *(float4*)&gp0[q * (LNB * G4) + nb * G4 + rbase] = acc;
                }
            }
        } else {
            if (it >= 1) {
                const float* src = p ? h1_lds : h0_lds;
                #pragma unroll 2
                for (int nb = 0; nb < LNB; ++nb) {
                    const float4* hq = (const float4*)&src[nb * HH + q * 16];
                    float4 h0v = hq[0], h1v = hq[1], h2v = hq[2], h3v = hq[3];
                    float4 acc;
                    acc.x = dot4(wq[0][0], h0v) + dot4(wq[0][1], h1v) + dot4(wq[0][2], h2v) + dot4(wq[0][3], h3v);
                    acc.y = dot4(wq[1][0], h0v) + dot4(wq[1][1], h1v) + dot4(wq[1][2], h2v) + dot4(wq[1][3], h3v);
                    acc.z = dot4(wq[2][0], h0v) + dot4(wq[2][1], h1v) + dot4(wq[2][2], h2v) + dot4(wq[2][3], h3v);
                    acc.w = dot4(wq[3][0], h0v) + dot4(wq[3][1], h1v) + dot4(wq[3][2], h2v) + dot4(wq[3][3], h3v);
                    if (hasBias) {
                        acc.x += bias4.x; acc.y += bias4.y;
                        acc.z += bias4.z; acc.w += bias4.w;
                    }
                    *(float4*)&gp1[(p * 4 + q) * (LNB * G4) + nb * G4 + rbase] = acc;
                }
            }
        }
        __syncthreads();
        // ======== combine phase ========
        if (tid < 256) {
            if (it < TT) {
                // cell a: k=c0k, cell b: k=c0k+32
                #pragma unroll
                for (int cc = 0; cc < 2; ++cc) {
                    const int k = c0k + cc * 32;
                    const int base = c0nb * G4 + k;
                    float gi = gp0[base] + gp0[2048 + base] + gp0[4096 + base] + gp0[6144 + base];
                    float gf = gp0[base + 64] + gp0[2048 + base + 64] + gp0[4096 + base + 64] + gp0[6144 + base + 64];
                    float gg = gp0[base + 128] + gp0[2048 + base + 128] + gp0[4096 + base + 128] + gp0[6144 + base + 128];
                    float go = gp0[base + 192] + gp0[2048 + base + 192] + gp0[4096 + base + 192] + gp0[6144 + base + 192];
                    float cprev = cc ? c_s0b : c_s0a;
                    float c = sigf(gf) * cprev + sigf(gi) * tanh_fast(gg);
                    if (cc) c_s0b = c; else c_s0a = c;
                    h0_lds[c0nb * HH + k] = sigf(go) * tanh_fast(c);
                }
            }
        } else {
            if (it >= 1) {
                const int base = c1nb * G4 + c1k;
                float gi = 0.f, gf = 0.f, gg = 0.f, go = 0.f;
                #pragma unroll
                for (int pp = 0; pp < 8; ++pp) {
                    const float* g8 = &gp1[pp * (LNB * G4) + base];
                    gi += g8[0];
                    gf += g8[64];
                    gg += g8[128];
                    go += g8[192];
                }
                float c = sigf(gf) * c_s1 + sigf(gi) * tanh_fast(gg);
                c_s1 = c;
                float h = sigf(go) * tanh_fast(c);
                h1_lds[c1nb * HH + c1k] = h;
                if (it == TT) x_out[(n0 + c1nb) * HH + c1k] = h;
            }
        }
        __syncthreads();
    }
}

// ---------- row_full: 1 if row i of rel_mask has NO edge ----------
__global__ void k_rowmask(const float* __restrict__ rel_mask, int* __restrict__ row_full)
{
    const int i = blockIdx.x;
    const int tid = threadIdx.x;
    bool found = false;
    for (int j = tid; j < NN; j += 256)
        found |= (rel_mask[i * NN + j] == 0.0f);
    __shared__ int s_any;
    if (tid == 0) s_any = 0;
    __syncthreads();
    if (found) atomicOr(&s_any, 1);
    __syncthreads();
    if (tid == 0) row_full[i] = s_any ? 0 : 1;
}

// ---------- h1 = x @ gat1_W ; es1/ed1 dots ----------
__global__ __launch_bounds__(256) void k_h1(
    const float* __restrict__ x, const float* __restrict__ W,
    const float* __restrict__ a_s, const float* __restrict__ a_d,
    float* __restrict__ h1g, float* __restrict__ es1, float* __restrict__ ed1)
{
    __shared__ float Wl[HH * GATH];
    __shared__ float xl[16 * 65];
    __shared__ float h1l[16 * GATH];
    const int tid = threadIdx.x;
    const int n0 = blockIdx.x * 16;
    for (int idx = tid; idx < HH * GATH; idx += 256) Wl[idx] = W[idx];
    for (int idx = tid; idx < 16 * HH; idx += 256) {
        int ln = idx >> 6, k = idx & 63;
        xl[ln * 65 + k] = x[(n0 + ln) * HH + k];
    }
    __syncthreads();
    const int ln = tid >> 4, jj = tid & 15;
    float acc = 0.0f;
    #pragma unroll 8
    for (int k = 0; k < HH; ++k) acc += xl[ln * 65 + k] * Wl[k * GATH + jj];
    h1g[(n0 + ln) * GATH + jj] = acc;
    h1l[ln * GATH + jj] = acc;
    __syncthreads();
    if (tid < 16) {
        float e_s = 0.0f, e_d = 0.0f;
        #pragma unroll
        for (int t = 0; t < GATH; ++t) {
            float hv = h1l[tid * GATH + t];
            e_s += hv * a_s[t];
            e_d += hv * a_d[t];
        }
        es1[n0 + tid] = e_s;
        ed1[n0 + tid] = e_d;
    }
}

// ---------- GAT1: column softmax (axis 0) + aggregate + relu ----------
__global__ __launch_bounds__(256) void k_gat1(
    const float* __restrict__ rel_mask, const int* __restrict__ row_full,
    const float* __restrict__ h1g, const float* __restrict__ es1,
    const float* __restrict__ ed1, const float* __restrict__ gat1_b,
    float* __restrict__ hrel)
{
    const int tid = threadIdx.x;
    const int c = tid & 7;
    const int r = tid >> 3;
    const int j = blockIdx.x * 8 + c;
    const float edj = ed1[j];
    float l = 0.0f;
    float o[GATH];
    #pragma unroll
    for (int t = 0; t < GATH; ++t) o[t] = 0.0f;

    for (int i = r; i < NN; i += 32) {
        float rm = rel_mask[i * NN + j];
        bool adj = (rm == 0.0f) || (i == j) || (row_full[i] != 0);
        if (adj) {
            float e = es1[i] + edj;
            e = (e > 0.0f) ? e : 0.2f * e;
            float p = __expf(e);
            l += p;
            const float4* hv = (const float4*)(h1g + i * GATH);
            #pragma unroll
            for (int q = 0; q < 4; ++q) {
                float4 h4 = hv[q];
                o[4 * q + 0] += p * h4.x;
                o[4 * q + 1] += p * h4.y;
                o[4 * q + 2] += p * h4.z;
                o[4 * q + 3] += p * h4.w;
            }
        }
    }
    __shared__ float s_l[256];
    __shared__ float s_o[256 * GATH];
    s_l[c * 32 + r] = l;
    #pragma unroll
    for (int t = 0; t < GATH; ++t) s_o[(c * 32 + r) * GATH + t] = o[t];
    __syncthreads();
    for (int step = 16; step >= 1; step >>= 1) {
        if (r < step) {
            int a = c * 32 + r, b = a + step;
            s_l[a] += s_l[b];
            #pragma unroll
            for (int t = 0; t < GATH; ++t) s_o[a * GATH + t] += s_o[b * GATH + t];
        }
        __syncthreads();
    }
    if (tid < 128) {
        int cc = tid >> 4, jj = tid & 15;
        float v = s_o[(cc * 32) * GATH + jj] / s_l[cc * 32] + gat1_b[jj];
        hrel[(blockIdx.x * 8 + cc) * GATH + jj] = fmaxf(v, 0.0f);
    }
}

// ---------- h2 = hrel @ gat2_W ; es2/ed2 ----------
__global__ __launch_bounds__(256) void k_h2(
    const float* __restrict__ hrel, const float* __restrict__ W2,
    const float* __restrict__ a_s, const float* __restrict__ a_d,
    float* __restrict__ h2g, float* __restrict__ es2, float* __restrict__ ed2)
{
    __shared__ float Wl[GATH * HH];
    __shared__ float hl[4 * 17];
    __shared__ float h2l[4 * HH];
    const int tid = threadIdx.x;
    const int n0 = blockIdx.x * 4;
    for (int idx = tid; idx < GATH * HH; idx += 256) Wl[idx] = W2[idx];
    if (tid < 64) {
        int ln = tid >> 4, k = tid & 15;
        hl[ln * 17 + k] = hrel[(n0 + ln) * GATH + k];
    }
    __syncthreads();
    const int ln = tid >> 6, jj = tid & 63;
    float acc = 0.0f;
    #pragma unroll
    for (int k = 0; k < GATH; ++k) acc += hl[ln * 17 + k] * Wl[k * HH + jj];
    h2g[(n0 + ln) * HH + jj] = acc;
    h2l[ln * HH + jj] = acc;
    __syncthreads();
    if (tid < 4) {
        float e_s = 0.0f, e_d = 0.0f;
        #pragma unroll 16
        for (int t = 0; t < HH; ++t) {
            float hv = h2l[tid * HH + t];
            e_s += hv * a_s[t];
            e_d += hv * a_d[t];
        }
        es2[n0 + tid] = e_s;
        ed2[n0 + tid] = e_d;
    }
}

// ---------- GAT2 + fc + leaky_relu ----------
__global__ __launch_bounds__(256) void k_gat2(
    const float* __restrict__ rel_mask, const int* __restrict__ row_full,
    const float* __restrict__ h2g, const float* __restrict__ es2,
    const float* __restrict__ ed2, const float* __restrict__ gat2_b,
    const float* __restrict__ fc_W, const float* __restrict__ fc_b,
    float* __restrict__ out)
{
    const int tid = threadIdx.x;
    const int c = tid & 7;
    const int r = tid >> 3;
    const int j = blockIdx.x * 8 + c;
    const float edj = ed2[j];
    float l = 0.0f;
    float o[HH];
    #pragma unroll
    for (int t = 0; t < HH; ++t) o[t] = 0.0f;

    for (int i = r; i < NN; i += 32) {
        float rm = rel_mask[i * NN + j];
        bool adj = (rm == 0.0f) || (i == j) || (row_full[i] != 0);
        if (adj) {
            float e = es2[i] + edj;
            e = (e > 0.0f) ? e : 0.2f * e;
            float p = __expf(e);
            l += p;
            const float4* hv = (const float4*)(h2g + (size_t)i * HH);
            #pragma unroll
            for (int q = 0; q < 16; ++q) {
                float4 h4 = hv[q];
                o[4 * q + 0] += p * h4.x;
                o[4 * q + 1] += p * h4.y;
                o[4 * q + 2] += p * h4.z;
                o[4 * q + 3] += p * h4.w;
            }
        }
    }
    __shared__ float s_l[256];
    __shared__ float s_o[256 * HH];   // 64 KB
    s_l[c * 32 + r] = l;
    #pragma unroll
    for (int t = 0; t < HH; ++t) s_o[(c * 32 + r) * HH + t] = o[t];
    __syncthreads();
    for (int step = 16; step >= 1; step >>= 1) {
        if (r < step) {
            int a = c * 32 + r, b = a + step;
            s_l[a] += s_l[b];
            #pragma unroll
            for (int t = 0; t < HH; ++t) s_o[a * HH + t] += s_o[b * HH + t];
        }
        __syncthreads();
    }
    __shared__ float s_out[8 * HH];
    {
        int cc = tid >> 5, jj = tid & 31;
        float linv = 1.0f / s_l[cc * 32];
        s_out[cc * HH + jj] = s_o[(cc * 32) * HH + jj] * linv + gat2_b[jj];
        s_out[cc * HH + jj + 32] = s_o[(cc * 32) * HH + jj + 32] * linv + gat2_b[jj + 32];
    }
    __syncthreads();
    if (tid < 8) {
        float acc = fc_b[0];
        #pragma unroll 16
        for (int t = 0; t < HH; ++t) acc += s_out[tid * HH + t] * fc_W[t];
        out[blockIdx.x * 8 + tid] = (acc > 0.0f) ? acc : 0.2f * acc;
    }
}

extern "C" void kernel_launch(void* const* d_in, const int* in_sizes, int n_in,
                              void* d_out, int out_size, void* d_ws, size_t ws_size,
                              hipStream_t stream)
{
    const float* inputs   = (const float*)d_in[0];
    // d_in[1] (relation), d_in[3] (rel_w_W), d_in[4] (rel_w_b) are dead:
    // softmax(rel_mask + weight) > 0 depends only on rel_mask.
    const float* rel_mask = (const float*)d_in[2];
    const float* w_ih0 = (const float*)d_in[5];
    const float* w_hh0 = (const float*)d_in[6];
    const float* b_ih0 = (const float*)d_in[7];
    const float* b_hh0 = (const float*)d_in[8];
    const float* w_ih1 = (const float*)d_in[9];
    const float* w_hh1 = (const float*)d_in[10];
    const float* b_ih1 = (const float*)d_in[11];
    const float* b_hh1 = (const float*)d_in[12];
    const float* gat1_W  = (const float*)d_in[13];
    const float* gat1_as = (const float*)d_in[14];
    const float* gat1_ad = (const float*)d_in[15];
    const float* gat1_b  = (const float*)d_in[16];
    const float* gat2_W  = (const float*)d_in[17];
    const float* gat2_as = (const float*)d_in[18];
    const float* gat2_ad = (const float*)d_in[19];
    const float* gat2_b  = (const float*)d_in[20];
    const float* fc_W = (const float*)d_in[21];
    const float* fc_b = (const float*)d_in[22];
    float* out = (float*)d_out;

    float* ws = (float*)d_ws;
    float* x_out = ws;                       // 2048*64
    float* h1g = x_out + NN * HH;            // 2048*16
    float* es1 = h1g + NN * GATH;            // 2048
    float* ed1 = es1 + NN;                   // 2048
    float* hrel = ed1 + NN;                  // 2048*16
    float* h2g = hrel + NN * GATH;           // 2048*64
    float* es2 = h2g + NN * HH;              // 2048
    float* ed2 = es2 + NN;                   // 2048
    int* row_full = (int*)(ed2 + NN);        // 2048

    k_lstm<<<NN / LNB, 768, 0, stream>>>(inputs, w_ih0, w_hh0, b_ih0, b_hh0,
                                         w_ih1, w_hh1, b_ih1, b_hh1, x_out);
    k_rowmask<<<NN, 256, 0, stream>>>(rel_mask, row_full);
    k_h1<<<NN / 16, 256, 0, stream>>>(x_out, gat1_W, gat1_as, gat1_ad, h1g, es1, ed1);
    k_gat1<<<NN / 8, 256, 0, stream>>>(rel_mask, row_full, h1g, es1, ed1, gat1_b, hrel);
    k_h2<<<NN / 4, 256, 0, stream>>>(hrel, gat2_W, gat2_as, gat2_ad, h2g, es2, ed2);
    k_gat2<<<NN / 8, 256, 0, stream>>>(rel_mask, row_full, h2g, es2, ed2, gat2_b,
                                       fc_W, fc_b, out);
}